// Round 12
// baseline (251.833 us; speedup 1.0000x reference)
//
#include <hip/hip_runtime.h>

typedef _Float16 hp2 __attribute__((ext_vector_type(2)));

#define NB    1024
#define TT    256
#define EE    100
#define VOCAB 5000
#define GG1   256   // 4*H1
#define GG2   128   // 4*H2

__device__ __forceinline__ float fast_sigmoid(float x) {
  return __builtin_amdgcn_rcpf(1.0f + __expf(-x));
}
__device__ __forceinline__ float fast_tanh(float x) {
  return 1.0f - 2.0f * __builtin_amdgcn_rcpf(1.0f + __expf(2.0f * x));
}

// ---- K1: emb_zi[v][u*4+g] = b1[g*64+u] + sum_k emb[v][k]*W1[k][g*64+u] ----
// Interleaved so L1 lane u grabs its 4 gate pre-activations as one float4.
__global__ __launch_bounds__(256) void emb_gemm(
    const float* __restrict__ emb, const float* __restrict__ W1,
    const float* __restrict__ b1, float* __restrict__ emb_zi)
{
  __shared__ float sE[8][EE];
  const int j  = threadIdx.x;           // column g*64+u
  const int v0 = blockIdx.x * 8;
  for (int idx = j; idx < 8 * EE; idx += 256) {
    int r = idx / EE, k = idx % EE;
    sE[r][k] = emb[(size_t)(v0 + r) * EE + k];
  }
  __syncthreads();
  float acc[8];
  const float bb = b1[j];
  #pragma unroll
  for (int r = 0; r < 8; ++r) acc[r] = bb;
  for (int k = 0; k < EE; ++k) {
    float w = W1[k * GG1 + j];
    #pragma unroll
    for (int r = 0; r < 8; ++r) acc[r] = fmaf(sE[r][k], w, acc[r]);
  }
  const int slot = (j & 63) * 4 + (j >> 6);   // u*4 + g
  #pragma unroll
  for (int r = 0; r < 8; ++r) emb_zi[(size_t)(v0 + r) * GG1 + slot] = acc[r];
}

// ---- K2: one wave = one batch row; A(t+1) || B(t) fused in one phase ----
// Lane u: L1 unit u complete (fdot2, per-lane activations).
// L2: unit u2 = u&31, k-half s = u>>5, one shfl_xor(32) reduce.
// sHB[2][96] f16: [0..63] = h1, [64..95] = h2. Iteration t: ALL reads from
// parity t&1 (h1(t), h2(t-1)); ALL writes to parity (t&1)^1 (h1(t+1), h2(t)).
// One barrier per step; A and B dot chains (8 independent) overlap latencies.
__global__ __launch_bounds__(64) __attribute__((amdgpu_waves_per_eu(1, 1)))
void lstm_row(
    const int* __restrict__ tokens, const float* __restrict__ emb_zi,
    const float* __restrict__ U1,
    const float* __restrict__ W2, const float* __restrict__ U2, const float* __restrict__ b2,
    const float* __restrict__ Wd, const float* __restrict__ bd,
    float* __restrict__ out)
{
  __shared__ __align__(16) _Float16 sHB[2][96];
  __shared__ int sTok[TT];

  const int u   = threadIdx.x;        // 0..63
  const int row = blockIdx.x;
  const int u2  = u & 31;             // L2 unit
  const int s   = u >> 5;             // L2 k-half

  // ---- L1 weights: wA[4p+g] = {U1[2p][g*64+u], U1[2p+1][g*64+u]}, p=0..31 ----
  hp2 wA[128];
  #pragma unroll
  for (int p = 0; p < 32; ++p) {
    #pragma unroll
    for (int g = 0; g < 4; ++g) {
      hp2 w;
      w[0] = (_Float16)U1[(2 * p + 0) * GG1 + g * 64 + u];
      w[1] = (_Float16)U1[(2 * p + 1) * GG1 + g * 64 + u];
      wA[4 * p + g] = w;
    }
  }
  // ---- L2 weights: k in [48s, 48s+48), pairs p=0..23; rows<64 -> W2, else U2 ----
  hp2 wB[96];
  #pragma unroll
  for (int p = 0; p < 24; ++p) {
    int k0 = 48 * s + 2 * p;          // even: never straddles the 64 boundary
    const float* r0 = (k0     < 64) ? &W2[(size_t)k0 * GG2]       : &U2[(size_t)(k0 - 64) * GG2];
    const float* r1 = (k0 + 1 < 64) ? &W2[(size_t)(k0 + 1) * GG2] : &U2[(size_t)(k0 + 1 - 64) * GG2];
    #pragma unroll
    for (int g = 0; g < 4; ++g) {
      hp2 w;
      w[0] = (_Float16)r0[g * 32 + u2];
      w[1] = (_Float16)r1[g * 32 + u2];
      wB[4 * p + g] = w;
    }
  }
  const float bi2 = b2[u2], bf2 = b2[32 + u2], bg2 = b2[64 + u2], bo2 = b2[96 + u2];

  // ---- init ----
  ((int4*)sTok)[u] = ((const int4*)(tokens + (size_t)row * TT))[u];
  sHB[0][u] = (_Float16)0.0f;
  sHB[1][u] = (_Float16)0.0f;
  if (u < 32) { sHB[0][64 + u] = (_Float16)0.0f; sHB[1][64 + u] = (_Float16)0.0f; }
  __syncthreads();

  float c1 = 0.f, h1r = 0.f, c2 = 0.f, h2r = 0.f;

  // ---- prologue A(0): h1(-1)=0 so z = z_x(0) only ----
  int tok_b = sTok[0];                 // token(t): B's mask
  {
    float4 zx0 = *(const float4*)&emb_zi[(size_t)tok_b * GG1 + 4 * u];
    if (tok_b != 0) {
      float iv = fast_sigmoid(zx0.x), fv = fast_sigmoid(zx0.y);
      float gv = fast_tanh(zx0.z),    ov = fast_sigmoid(zx0.w);
      (void)fv;
      c1 = iv * gv; h1r = ov * fast_tanh(c1);
    }
    sHB[0][u] = (_Float16)h1r;
  }
  int   tok_a = sTok[1];               // token(t+1): A's mask
  float4 zxa = *(const float4*)&emb_zi[(size_t)tok_a * GG1 + 4 * u];
  __syncthreads();

  for (int t = 0; t < TT; ++t) {
    const _Float16* rb = sHB[t & 1];
    _Float16*       wb = (_Float16*)sHB[(t & 1) ^ 1];

    // prefetch token/z_x for step t+2 (consumed next iteration as zxa)
    int tok_n = 0;
    float4 zxn = zxa;
    if (t + 2 < TT) {
      tok_n = sTok[t + 2];
      zxn = *(const float4*)&emb_zi[(size_t)tok_n * GG1 + 4 * u];
    }

    // ---- A(t+1) dots: z = z_x(t+1) + U1 . h1(t) ----
    float a0 = zxa.x, a1 = zxa.y, a2 = zxa.z, a3 = zxa.w;
    #pragma unroll
    for (int q = 0; q < 8; ++q) {                 // uniform b128 reads of h1(t)
      int4 hq = ((const int4*)rb)[q];
      #pragma unroll
      for (int pp = 0; pp < 4; ++pp) {
        hp2 hv = ((const hp2*)&hq)[pp];
        const int p = 4 * q + pp;
        a0 = __builtin_amdgcn_fdot2(hv, wA[4 * p + 0], a0, false);
        a1 = __builtin_amdgcn_fdot2(hv, wA[4 * p + 1], a1, false);
        a2 = __builtin_amdgcn_fdot2(hv, wA[4 * p + 2], a2, false);
        a3 = __builtin_amdgcn_fdot2(hv, wA[4 * p + 3], a3, false);
      }
    }

    // ---- B(t) dots: lane half s reads k in [48s, 48s+48) of [h1(t)|h2(t-1)] ----
    float b0 = 0.f, b1v = 0.f, b2v = 0.f, b3 = 0.f;
    const int4* hbp = (const int4*)(rb + 48 * s);  // 2 distinct addrs/wave: free
    #pragma unroll
    for (int q = 0; q < 6; ++q) {
      int4 hq = hbp[q];
      #pragma unroll
      for (int pp = 0; pp < 4; ++pp) {
        hp2 hv = ((const hp2*)&hq)[pp];
        const int p = 4 * q + pp;
        b0  = __builtin_amdgcn_fdot2(hv, wB[4 * p + 0], b0,  false);
        b1v = __builtin_amdgcn_fdot2(hv, wB[4 * p + 1], b1v, false);
        b2v = __builtin_amdgcn_fdot2(hv, wB[4 * p + 2], b2v, false);
        b3  = __builtin_amdgcn_fdot2(hv, wB[4 * p + 3], b3,  false);
      }
    }

    // ---- B(t) finish ----
    b0  += __shfl_xor(b0, 32);
    b1v += __shfl_xor(b1v, 32);
    b2v += __shfl_xor(b2v, 32);
    b3  += __shfl_xor(b3, 32);
    {
      const bool mb = (tok_b != 0);
      float i2 = fast_sigmoid(b0 + bi2);
      float f2 = fast_sigmoid(b1v + bf2);
      float g2 = fast_tanh(b2v + bg2);
      float o2 = fast_sigmoid(b3 + bo2);
      if (mb) { c2 = f2 * c2 + i2 * g2; h2r = o2 * fast_tanh(c2); }
    }
    if (s == 0) wb[64 + u2] = (_Float16)h2r;

    // ---- A(t+1) finish ----
    {
      const bool ma = (tok_a != 0);
      float iv = fast_sigmoid(a0);
      float fv = fast_sigmoid(a1);
      float gv = fast_tanh(a2);
      float ov = fast_sigmoid(a3);
      if (ma) { c1 = fv * c1 + iv * gv; h1r = ov * fast_tanh(c1); }
    }
    wb[u] = (_Float16)h1r;
    __syncthreads();

    tok_b = tok_a; tok_a = tok_n; zxa = zxn;
  }

  // ---- epilogue: h2(TT-1) is in parity ((TT-1)&1)^1 = 0 ----
  if (u < 4) {
    float a = bd[u];
    #pragma unroll
    for (int k = 0; k < 32; ++k)
      a = fmaf((float)sHB[0][64 + k], Wd[k * 4 + u], a);
    out[(size_t)row * 4 + u] = fast_sigmoid(a);
  }
}

extern "C" void kernel_launch(void* const* d_in, const int* in_sizes, int n_in,
                              void* d_out, int out_size, void* d_ws, size_t ws_size,
                              hipStream_t stream) {
  const int*   tokens = (const int*)d_in[0];
  const float* emb    = (const float*)d_in[1];
  const float* W1     = (const float*)d_in[2];
  const float* U1     = (const float*)d_in[3];
  const float* b1     = (const float*)d_in[4];
  const float* W2     = (const float*)d_in[5];
  const float* U2     = (const float*)d_in[6];
  const float* b2     = (const float*)d_in[7];
  const float* Wd     = (const float*)d_in[8];
  const float* bd     = (const float*)d_in[9];
  float* out    = (float*)d_out;
  float* emb_zi = (float*)d_ws;         // 5000*256*4 = 5.12 MB scratch

  emb_gemm<<<dim3(VOCAB / 8), dim3(256), 0, stream>>>(emb, W1, b1, emb_zi);
  lstm_row<<<dim3(NB), dim3(64), 0, stream>>>(
      tokens, emb_zi, U1, W2, U2, b2, Wd, bd, out);
}